// Round 1
// baseline (755.603 us; speedup 1.0000x reference)
//
#include <hip/hip_runtime.h>

#define S0V 25
#define S1V 10
#define NBATCH 4096
#define FDIM 128
#define NNODES 1000000
#define L1N (NBATCH * 11)   // 45056 level-1 nodes

typedef __attribute__((ext_vector_type(8))) short short8;
typedef __attribute__((ext_vector_type(4))) float f32x4;

__device__ __forceinline__ ushort f2bf(float f) {
  unsigned int x = __builtin_bit_cast(unsigned int, f);
  x += 0x7fffu + ((x >> 16) & 1u);   // round-to-nearest-even
  return (ushort)(x >> 16);
}
__device__ __forceinline__ float bf2f(ushort u) {
  unsigned int x = ((unsigned int)u) << 16;
  return __builtin_bit_cast(float, x);
}

// ---------------------------------------------------------------------------
// Prep: convert W0,W1 (fp32 [128,256]) to bf16 once. 64 blocks x 256 thr.
// ---------------------------------------------------------------------------
__global__ __launch_bounds__(256) void prep_w_kernel(
    const float* __restrict__ W0, const float* __restrict__ W1,
    ushort* __restrict__ Wb0, ushort* __restrict__ Wb1) {
  const int idx = blockIdx.x * 256 + threadIdx.x;   // 16384 threads, 4 elems each
  const int sel = idx >> 13;                        // 0: W0, 1: W1 (8192 float4 each)
  const int k = idx & 8191;
  const float4 v = sel ? ((const float4*)W1)[k] : ((const float4*)W0)[k];
  ushort4 h;
  h.x = f2bf(v.x); h.y = f2bf(v.y); h.z = f2bf(v.z); h.w = f2bf(v.w);
  if (sel) ((ushort4*)Wb1)[k] = h; else ((ushort4*)Wb0)[k] = h;
}

// ---------------------------------------------------------------------------
// Shared GEMM+epilogue: out_rows = l2norm(relu(Xs[64,256] @ Wb[128,256]^T + b))
// 512 threads = 8 waves. Wave w: m-frag = w&3 (16 rows), col-half = w>>2
// (64 cols = 4 n-frags). K staged from global bf16 W in 64-col chunks.
// mfma_f32_16x16x32_bf16 layouts (m89/m91-verified): A[m=lane&15][k=q*8+j],
// B^T row-major same; C: col=lane&15, row=q*4+reg.
// Row sum-of-squares crosses the two col-half waves -> combined via ssb LDS.
// ---------------------------------------------------------------------------
template <int OUT_BF16>
__device__ __forceinline__ void gemm_norm_64(
    ushort* __restrict__ Xs,   // [64][264] bf16 LDS
    ushort* __restrict__ Wt,   // [128][72] bf16 LDS staging
    float* __restrict__ ssb,   // [64][2] LDS
    const ushort* __restrict__ Wb, const float* __restrict__ bias,
    void* __restrict__ outp, int row0) {
  const int tid = threadIdx.x;
  const int wave = tid >> 6, lane = tid & 63;
  const int q = lane >> 4, r = lane & 15;
  const int mf = wave & 3, ch = wave >> 2;

  f32x4 acc[4] = {};
#pragma unroll
  for (int kt = 0; kt < 4; ++kt) {
    // stage W chunk: 128 rows x 64 cols bf16 = 1024 short8; 512 thr x 2
#pragma unroll
    for (int p = 0; p < 2; ++p) {
      const int idx = tid + p * 512;
      const int row = idx >> 3, cc = idx & 7;
      const short8 v = *(const short8*)(Wb + row * 256 + kt * 64 + cc * 8);
      *(short8*)(Wt + row * 72 + cc * 8) = v;
    }
    __syncthreads();
#pragma unroll
    for (int kk = 0; kk < 2; ++kk) {
      const int koff = kk * 32 + q * 8;
      const short8 a = *(const short8*)(Xs + (mf * 16 + r) * 264 + kt * 64 + koff);
#pragma unroll
      for (int nf = 0; nf < 4; ++nf) {
        const short8 bb = *(const short8*)(Wt + (ch * 64 + nf * 16 + r) * 72 + koff);
        acc[nf] = __builtin_amdgcn_mfma_f32_16x16x32_bf16(a, bb, acc[nf], 0, 0, 0);
      }
    }
    __syncthreads();
  }

  float bv[4];
#pragma unroll
  for (int nf = 0; nf < 4; ++nf) bv[nf] = bias[ch * 64 + nf * 16 + r];

  float ss[4] = {0.f, 0.f, 0.f, 0.f};
#pragma unroll
  for (int nf = 0; nf < 4; ++nf)
#pragma unroll
    for (int reg = 0; reg < 4; ++reg) {
      float v = acc[nf][reg] + bv[nf];
      v = fmaxf(v, 0.f);
      acc[nf][reg] = v;
      ss[reg] += v * v;
    }
  // reduce over the 16 lanes of the quad (cols within this half)
#pragma unroll
  for (int off = 1; off < 16; off <<= 1)
#pragma unroll
    for (int reg = 0; reg < 4; ++reg) ss[reg] += __shfl_xor(ss[reg], off, 16);
  // combine the two col-halves through LDS
  if (r == 0) {
#pragma unroll
    for (int reg = 0; reg < 4; ++reg)
      ssb[(mf * 16 + q * 4 + reg) * 2 + ch] = ss[reg];
  }
  __syncthreads();
#pragma unroll
  for (int reg = 0; reg < 4; ++reg) {
    const int lrow = mf * 16 + q * 4 + reg;
    const float tot = ssb[lrow * 2] + ssb[lrow * 2 + 1];
    const float inv = 1.f / fmaxf(sqrtf(tot), 1e-12f);
#pragma unroll
    for (int nf = 0; nf < 4; ++nf) {
      const int col = ch * 64 + nf * 16 + r;
      const float v = acc[nf][reg] * inv;
      if (OUT_BF16)
        ((ushort*)outp)[(size_t)(row0 + lrow) * 128 + col] = f2bf(v);
      else
        ((float*)outp)[(size_t)(row0 + lrow) * 128 + col] = v;
    }
  }
}

// ---------------------------------------------------------------------------
// Fused layer 1 — PROBE BUILD: body executed twice per block.
//   rep 0: indices shifted by +499979 mod N (statistically identical fresh
//          random gather), output to scratch H1s — makes this dispatch
//          ~2x its true cost so it clears the top-5 cutoff (~311us) set by
//          the harness's 2GB poison fills and reports its own counters
//          (hbm_gbps of the gather, FETCH_SIZE, VALUBusy, Occupancy).
//   rep 1: the real computation, bit-identical to the 664us baseline.
// dur_us delta vs baseline == true fused_l1 duration.
// ---------------------------------------------------------------------------
__global__ __launch_bounds__(512, 4) void fused_l1_kernel(
    const float* __restrict__ feat, const int* __restrict__ nodes,
    const int* __restrict__ nbr1, const int* __restrict__ nbr0,
    const ushort* __restrict__ Wb0, const float* __restrict__ b0,
    ushort* __restrict__ H1, ushort* __restrict__ H1s) {
  __shared__ ushort Xs[64 * 264];
  __shared__ ushort Wt[128 * 72];
  __shared__ float ssb[128];
  const int tid = threadIdx.x;
  const int wave = tid >> 6, lane = tid & 63;
  const int half = lane >> 5, l = lane & 31;
  const int i0 = blockIdx.x * 64;

#pragma unroll 1
  for (int rep = 0; rep < 2; ++rep) {
    const int shift = (rep == 0) ? 499979 : 0;
    for (int t = 0; t < 8; ++t) {
      const int row = wave * 8 + t;
      const int i = i0 + row;
      const int b = i / 11;
      const int j = i - b * 11;
      int self = (j == 0) ? nodes[b] : nbr1[b * S1V + (j - 1)];
      self += shift; if (self >= NNODES) self -= NNODES;
      int myidx = nbr0[(size_t)i * S0V + ((lane < S0V) ? lane : 0)];
      myidx += shift; if (myidx >= NNODES) myidx -= NNODES;

      float4 acc = make_float4(0.f, 0.f, 0.f, 0.f);
#pragma unroll
      for (int k = 0; k < 12; ++k) {
        const int rr = __shfl(myidx, 2 * k + half);
        const float4 v = *(const float4*)(feat + (size_t)rr * FDIM + l * 4);
        acc.x += v.x; acc.y += v.y; acc.z += v.z; acc.w += v.w;
      }
      {  // s = 24: both halves load the same row, only half 0 accumulates
        const int rr = __shfl(myidx, 24);
        const float4 v = *(const float4*)(feat + (size_t)rr * FDIM + l * 4);
        if (half == 0) { acc.x += v.x; acc.y += v.y; acc.z += v.z; acc.w += v.w; }
      }
      acc.x += __shfl_xor(acc.x, 32);
      acc.y += __shfl_xor(acc.y, 32);
      acc.z += __shfl_xor(acc.z, 32);
      acc.w += __shfl_xor(acc.w, 32);

      const float4 sv = *(const float4*)(feat + (size_t)self * FDIM + l * 4);
      float4 val;
      if (half == 0) {
        val = sv;
      } else {
        val.x = acc.x * (1.f / 25.f); val.y = acc.y * (1.f / 25.f);
        val.z = acc.z * (1.f / 25.f); val.w = acc.w * (1.f / 25.f);
      }
      ushort4 h;
      h.x = f2bf(val.x); h.y = f2bf(val.y); h.z = f2bf(val.z); h.w = f2bf(val.w);
      *(ushort4*)(Xs + row * 264 + half * 128 + l * 4) = h;
    }
    __syncthreads();
    gemm_norm_64<1>(Xs, Wt, ssb, Wb0, b0, rep ? (void*)H1 : (void*)H1s, i0);
  }
}

// ---------------------------------------------------------------------------
// Fused layer 2: build X2 tile [self ; mean(10 nbr reps)] in LDS from H1,
// then GEMM W1 -> relu -> l2norm -> d_out (f32). 64 targets/block, grid 64.
// ---------------------------------------------------------------------------
__global__ __launch_bounds__(512, 4) void fused_l2_kernel(
    const ushort* __restrict__ H1, const ushort* __restrict__ Wb1,
    const float* __restrict__ b1, float* __restrict__ out) {
  __shared__ ushort Xs[64 * 264];
  __shared__ ushort Wt[128 * 72];
  __shared__ float ssb[128];
  const int tid = threadIdx.x;
  const int wave = tid >> 6, lane = tid & 63;
  const int t0 = blockIdx.x * 64;

  for (int t = 0; t < 8; ++t) {
    const int row = wave * 8 + t;
    const ushort* base = H1 + (size_t)(t0 + row) * 11 * 128;
    const ushort2 s = *(const ushort2*)(base + lane * 2);
    float ax = 0.f, ay = 0.f;
#pragma unroll
    for (int j = 1; j <= 10; ++j) {
      const ushort2 v = *(const ushort2*)(base + j * 128 + lane * 2);
      ax += bf2f(v.x); ay += bf2f(v.y);
    }
    *(ushort2*)(Xs + row * 264 + lane * 2) = s;
    ushort2 m;
    m.x = f2bf(ax * 0.1f); m.y = f2bf(ay * 0.1f);
    *(ushort2*)(Xs + row * 264 + 128 + lane * 2) = m;
  }
  __syncthreads();
  gemm_norm_64<0>(Xs, Wt, ssb, Wb1, b1, (void*)out, t0);
}

extern "C" void kernel_launch(void* const* d_in, const int* in_sizes, int n_in,
                              void* d_out, int out_size, void* d_ws, size_t ws_size,
                              hipStream_t stream) {
  const float* feat  = (const float*)d_in[0];   // [1e6,128]
  const float* W0    = (const float*)d_in[1];   // [128,256]
  const float* b0    = (const float*)d_in[2];   // [128]
  const float* W1    = (const float*)d_in[3];   // [128,256]
  const float* b1    = (const float*)d_in[4];   // [128]
  const int* nodes   = (const int*)d_in[5];     // [4096]
  const int* nbr1    = (const int*)d_in[6];     // [4096,10]
  const int* nbr0    = (const int*)d_in[7];     // [4096,11,25]
  float* out = (float*)d_out;                   // [4096,128] f32

  // workspace layout (16B aligned). The harness's 2GB poison fill implies
  // ws_size = 2.048e9 B; scratch for the probe pass lives at +16 MB.
  ushort* Wb0 = (ushort*)d_ws;                              // 65,536 B
  ushort* Wb1 = (ushort*)((char*)d_ws + 65536);             // 65,536 B
  ushort* H1  = (ushort*)((char*)d_ws + 131072);            // 45056*128*2 = 11,534,336 B
  ushort* H1s = (ushort*)((char*)d_ws + (size_t)16 * 1024 * 1024);  // probe scratch, same size

  // P: W0,W1 -> bf16 once
  prep_w_kernel<<<64, 256, 0, stream>>>(W0, W1, Wb0, Wb1);
  // L1 fused (PROBE: 2x body; pass 1 is the real one): gather+mean -> GEMM -> H1
  fused_l1_kernel<<<L1N / 64, 512, 0, stream>>>(feat, nodes, nbr1, nbr0, Wb0, b0, H1, H1s);
  // L2 fused: X2 build -> GEMM -> z f32 [4096,128]
  fused_l2_kernel<<<NBATCH / 64, 512, 0, stream>>>(H1, Wb1, b1, out);
}